// Round 2
// baseline (203.795 us; speedup 1.0000x reference)
//
#include <hip/hip_runtime.h>
#include <hip/hip_bf16.h>

// GCN SpMM: out[i,d] = sum_{e: rows[e]==i} vals[e] * embeds[cols[e], d]
// rows sorted ascending. E=1.6M, N=100k, D=64.
//
// Layout: wave = 4 subgroups of 16 lanes. Subgroup s owns 128 contiguous
// edges; lane t within a subgroup owns features [4t, 4t+4) as float4.
// Gather for one edge = 16 lanes x 16B = one 256B line, and the 4 subgroups
// issue 4 independent lines per load instruction. Depth-2 prefetch keeps 2
// load instructions (8 lines) in flight per wave -> ~8x MLP vs round 1.

constexpr int D = 64;
constexpr int SG = 16;             // lanes per subgroup
constexpr int SG_PER_WAVE = 4;
constexpr int EDGES_PER_SG = 128;  // contiguous edges per subgroup

__global__ __launch_bounds__(256) void zero_kernel(float4* __restrict__ out4, int n4) {
    int i = blockIdx.x * blockDim.x + threadIdx.x;
    if (i < n4) out4[i] = make_float4(0.f, 0.f, 0.f, 0.f);
}

__global__ __launch_bounds__(256) void spmm_kernel(
    const int* __restrict__ rows,
    const int* __restrict__ cols,
    const float* __restrict__ vals,
    const float4* __restrict__ embeds4,   // [N, 16] float4 view of [N, 64] f32
    float* __restrict__ out,
    int n_edges)
{
    const int lane = threadIdx.x & 63;
    const int s    = lane >> 4;           // subgroup 0..3
    const int t    = lane & 15;           // lane within subgroup
    const int wave = blockIdx.x * (blockDim.x >> 6) + (threadIdx.x >> 6);
    const int g    = wave * SG_PER_WAVE + s;

    long e0 = (long)g * EDGES_PER_SG;
    long e1 = e0 + EDGES_PER_SG;
    if (e0 > n_edges) e0 = n_edges;
    if (e1 > n_edges) e1 = n_edges;

    float4 acc = make_float4(0.f, 0.f, 0.f, 0.f);
    int cur_row = -1;
    const int sbase = s << 4;

    for (long base = e0; base < e1; base += SG) {
        int cnt = (int)((e1 - base) < (long)SG ? (e1 - base) : (long)SG);
        // coalesced metadata load: 16 consecutive edges per subgroup
        int r = 0, c = 0; float v = 0.f;
        if (t < cnt) {
            long e = base + t;
            r = rows[e]; c = cols[e]; v = vals[e];
        }
        // prefetch edge 0's embedding line
        int c0 = __shfl(c, sbase | 0);
        float4 emb = embeds4[(long)c0 * SG + t];

        for (int j = 0; j < cnt; ++j) {
            int   rj = __shfl(r, sbase | j);
            float vj = __shfl(v, sbase | j);
            float4 cur = emb;
            int jn = j + 1;
            if (jn < cnt) {                       // issue next load before using cur
                int cn = __shfl(c, sbase | jn);
                emb = embeds4[(long)cn * SG + t];
            }
            if (rj != cur_row) {                  // subgroup-uniform branch
                if (cur_row >= 0) {
                    float* o = out + (long)cur_row * D + (t << 2);
                    atomicAdd(o + 0, acc.x);
                    atomicAdd(o + 1, acc.y);
                    atomicAdd(o + 2, acc.z);
                    atomicAdd(o + 3, acc.w);
                }
                cur_row = rj;
                acc = make_float4(0.f, 0.f, 0.f, 0.f);
            }
            acc.x += vj * cur.x;
            acc.y += vj * cur.y;
            acc.z += vj * cur.z;
            acc.w += vj * cur.w;
        }
    }
    if (cur_row >= 0) {
        float* o = out + (long)cur_row * D + (t << 2);
        atomicAdd(o + 0, acc.x);
        atomicAdd(o + 1, acc.y);
        atomicAdd(o + 2, acc.z);
        atomicAdd(o + 3, acc.w);
    }
}

extern "C" void kernel_launch(void* const* d_in, const int* in_sizes, int n_in,
                              void* d_out, int out_size, void* d_ws, size_t ws_size,
                              hipStream_t stream) {
    const int*    rows    = (const int*)d_in[0];
    const int*    cols    = (const int*)d_in[1];
    const float*  vals    = (const float*)d_in[2];
    const float4* embeds4 = (const float4*)d_in[3];
    float*        out     = (float*)d_out;

    const int n_edges = in_sizes[0];

    // 1) zero-init output (poisoned to 0xAA before every launch)
    int n4 = out_size / 4;                         // 1.6M float4
    int zb = (n4 + 255) / 256;
    zero_kernel<<<zb, 256, 0, stream>>>((float4*)out, n4);

    // 2) segmented SpMM
    int subgroups = (n_edges + EDGES_PER_SG - 1) / EDGES_PER_SG;
    int waves     = (subgroups + SG_PER_WAVE - 1) / SG_PER_WAVE;
    int blocks    = (waves + 3) / 4;               // 4 waves per 256-thread block
    spmm_kernel<<<blocks, 256, 0, stream>>>(rows, cols, vals, embeds4, out, n_edges);
}

// Round 3
// 142.878 us; speedup vs baseline: 1.4264x; 1.4264x over previous
//
#include <hip/hip_runtime.h>
#include <hip/hip_bf16.h>

// GCN SpMM: out[i,d] = sum_{e: rows[e]==i} vals[e] * embeds[cols[e], d]
// rows sorted ascending. E=1.6M, N=100k, D=64.
//
// Node-centric CSR formulation:
//  1) rowptr_kernel builds row_ptr[N+1] in d_ws (row_ptr[i] = first edge with
//     rows[e] >= i) from the sorted rows array. One thread per edge.
//  2) spmm_node_kernel: one 16-lane subgroup per node; lane t owns features
//     [4t,4t+4) as float4. 4-deep unrolled gather => 4 independent load
//     instructions in flight per wave (each covering 4 subgroups' 256B lines).
//     One coalesced float4 store per node -- no atomics, no zero pass
//     (zero-degree nodes store acc==0).

constexpr int D = 64;

__global__ __launch_bounds__(256) void rowptr_kernel(
    const int* __restrict__ rows, int* __restrict__ row_ptr,
    int n_edges, int n_nodes)
{
    int e = blockIdx.x * blockDim.x + threadIdx.x;
    if (e >= n_edges) return;
    int r_cur  = rows[e];
    int r_prev = (e == 0) ? -1 : rows[e - 1];
    for (int r = r_prev + 1; r <= r_cur; ++r) row_ptr[r] = e;
    if (e == n_edges - 1)
        for (int r = r_cur + 1; r <= n_nodes; ++r) row_ptr[r] = n_edges;
}

__global__ __launch_bounds__(256) void spmm_node_kernel(
    const int* __restrict__ row_ptr,
    const int* __restrict__ cols,
    const float* __restrict__ vals,
    const float4* __restrict__ embeds4,   // [N,16] float4 view of [N,64] f32
    float4* __restrict__ out4,            // [N,16] float4 view
    int n_nodes)
{
    const int lane = threadIdx.x & 63;
    const int t    = lane & 15;           // feature quad
    const int s    = lane >> 4;           // subgroup within wave
    const int wave = blockIdx.x * (blockDim.x >> 6) + (threadIdx.x >> 6);
    const int node = wave * 4 + s;
    if (node >= n_nodes) return;

    const int lo = row_ptr[node];
    const int hi = row_ptr[node + 1];

    float4 acc = make_float4(0.f, 0.f, 0.f, 0.f);
    int e = lo;
    for (; e + 4 <= hi; e += 4) {
        int   c0 = cols[e + 0], c1 = cols[e + 1], c2 = cols[e + 2], c3 = cols[e + 3];
        float v0 = vals[e + 0], v1 = vals[e + 1], v2 = vals[e + 2], v3 = vals[e + 3];
        float4 m0 = embeds4[(long)c0 * 16 + t];
        float4 m1 = embeds4[(long)c1 * 16 + t];
        float4 m2 = embeds4[(long)c2 * 16 + t];
        float4 m3 = embeds4[(long)c3 * 16 + t];
        acc.x += v0 * m0.x; acc.y += v0 * m0.y; acc.z += v0 * m0.z; acc.w += v0 * m0.w;
        acc.x += v1 * m1.x; acc.y += v1 * m1.y; acc.z += v1 * m1.z; acc.w += v1 * m1.w;
        acc.x += v2 * m2.x; acc.y += v2 * m2.y; acc.z += v2 * m2.z; acc.w += v2 * m2.w;
        acc.x += v3 * m3.x; acc.y += v3 * m3.y; acc.z += v3 * m3.z; acc.w += v3 * m3.w;
    }
    for (; e < hi; ++e) {
        int c = cols[e]; float v = vals[e];
        float4 m = embeds4[(long)c * 16 + t];
        acc.x += v * m.x; acc.y += v * m.y; acc.z += v * m.z; acc.w += v * m.w;
    }
    out4[(long)node * 16 + t] = acc;
}

extern "C" void kernel_launch(void* const* d_in, const int* in_sizes, int n_in,
                              void* d_out, int out_size, void* d_ws, size_t ws_size,
                              hipStream_t stream) {
    const int*    rows    = (const int*)d_in[0];
    const int*    cols    = (const int*)d_in[1];
    const float*  vals    = (const float*)d_in[2];
    const float4* embeds4 = (const float4*)d_in[3];
    float4*       out4    = (float4*)d_out;

    const int n_edges = in_sizes[0];
    const int n_nodes = out_size / D;     // 100000

    int* row_ptr = (int*)d_ws;            // (n_nodes+1) ints, ~400 KB

    // 1) build CSR row pointers from sorted rows
    int rb = (n_edges + 255) / 256;
    rowptr_kernel<<<rb, 256, 0, stream>>>(rows, row_ptr, n_edges, n_nodes);

    // 2) node-centric SpMM: one 16-lane subgroup per node
    int waves  = (n_nodes + 3) / 4;       // 4 nodes per wave
    int blocks = (waves + 3) / 4;         // 4 waves per 256-thread block
    spmm_node_kernel<<<blocks, 256, 0, stream>>>(row_ptr, cols, vals, embeds4, out4, n_nodes);
}

// Round 4
// 142.073 us; speedup vs baseline: 1.4344x; 1.0057x over previous
//
#include <hip/hip_runtime.h>
#include <hip/hip_bf16.h>

// GCN SpMM: out[i,d] = sum_{e: rows[e]==i} vals[e] * embeds[cols[e], d]
// rows sorted ascending. E=1.6M, N=100k, D=64.
//
// Node-centric CSR:
//  1) rowptr_kernel builds row_ptr[N+1] in d_ws from the sorted rows.
//  2) spmm_node_kernel: one 16-lane subgroup per node; lane t owns features
//     [4t,4t+4) as float4. Edges processed in chunks of 8 with ALL 8 embed
//     loads explicitly live simultaneously (8-deep MLP per wave; each load
//     instruction covers 4 subgroups x 256B = 16 cache lines). Tail edges are
//     predicated: index clamped to hi-1 (L1 same-line hit, no extra fabric
//     traffic), val zeroed. One coalesced float4 store per node; no atomics,
//     no zero pass.

constexpr int D = 64;

__global__ __launch_bounds__(256) void rowptr_kernel(
    const int* __restrict__ rows, int* __restrict__ row_ptr,
    int n_edges, int n_nodes)
{
    int e = blockIdx.x * blockDim.x + threadIdx.x;
    if (e >= n_edges) return;
    int r_cur  = rows[e];
    int r_prev = (e == 0) ? -1 : rows[e - 1];
    for (int r = r_prev + 1; r <= r_cur; ++r) row_ptr[r] = e;
    if (e == n_edges - 1)
        for (int r = r_cur + 1; r <= n_nodes; ++r) row_ptr[r] = n_edges;
}

__global__ __launch_bounds__(256) void spmm_node_kernel(
    const int* __restrict__ row_ptr,
    const int* __restrict__ cols,
    const float* __restrict__ vals,
    const float4* __restrict__ embeds4,   // [N,16] float4 view of [N,64] f32
    float4* __restrict__ out4,            // [N,16] float4 view
    int n_nodes)
{
    const int lane = threadIdx.x & 63;
    const int t    = lane & 15;           // feature quad
    const int s    = lane >> 4;           // subgroup within wave
    const int wave = blockIdx.x * (blockDim.x >> 6) + (threadIdx.x >> 6);
    const int node = wave * 4 + s;
    if (node >= n_nodes) return;

    const int lo = row_ptr[node];
    const int hi = row_ptr[node + 1];

    float4 acc = make_float4(0.f, 0.f, 0.f, 0.f);

    for (int e = lo; e < hi; e += 8) {
        const int last = hi - 1;
        // clamped indices: always valid addresses; tail duplicates hit L1
        int i0 = e;                                   // e < hi, always valid
        int i1 = (e + 1 <= last) ? e + 1 : last;
        int i2 = (e + 2 <= last) ? e + 2 : last;
        int i3 = (e + 3 <= last) ? e + 3 : last;
        int i4 = (e + 4 <= last) ? e + 4 : last;
        int i5 = (e + 5 <= last) ? e + 5 : last;
        int i6 = (e + 6 <= last) ? e + 6 : last;
        int i7 = (e + 7 <= last) ? e + 7 : last;

        int c0 = cols[i0], c1 = cols[i1], c2 = cols[i2], c3 = cols[i3];
        int c4 = cols[i4], c5 = cols[i5], c6 = cols[i6], c7 = cols[i7];

        float v0 = vals[i0];
        float v1 = (e + 1 < hi) ? vals[i1] : 0.f;
        float v2 = (e + 2 < hi) ? vals[i2] : 0.f;
        float v3 = (e + 3 < hi) ? vals[i3] : 0.f;
        float v4 = (e + 4 < hi) ? vals[i4] : 0.f;
        float v5 = (e + 5 < hi) ? vals[i5] : 0.f;
        float v6 = (e + 6 < hi) ? vals[i6] : 0.f;
        float v7 = (e + 7 < hi) ? vals[i7] : 0.f;

        // 8 independent gathers, all live before first use -> 8-deep MLP
        float4 m0 = embeds4[(long)c0 * 16 + t];
        float4 m1 = embeds4[(long)c1 * 16 + t];
        float4 m2 = embeds4[(long)c2 * 16 + t];
        float4 m3 = embeds4[(long)c3 * 16 + t];
        float4 m4 = embeds4[(long)c4 * 16 + t];
        float4 m5 = embeds4[(long)c5 * 16 + t];
        float4 m6 = embeds4[(long)c6 * 16 + t];
        float4 m7 = embeds4[(long)c7 * 16 + t];

        acc.x += v0 * m0.x; acc.y += v0 * m0.y; acc.z += v0 * m0.z; acc.w += v0 * m0.w;
        acc.x += v1 * m1.x; acc.y += v1 * m1.y; acc.z += v1 * m1.z; acc.w += v1 * m1.w;
        acc.x += v2 * m2.x; acc.y += v2 * m2.y; acc.z += v2 * m2.z; acc.w += v2 * m2.w;
        acc.x += v3 * m3.x; acc.y += v3 * m3.y; acc.z += v3 * m3.z; acc.w += v3 * m3.w;
        acc.x += v4 * m4.x; acc.y += v4 * m4.y; acc.z += v4 * m4.z; acc.w += v4 * m4.w;
        acc.x += v5 * m5.x; acc.y += v5 * m5.y; acc.z += v5 * m5.z; acc.w += v5 * m5.w;
        acc.x += v6 * m6.x; acc.y += v6 * m6.y; acc.z += v6 * m6.z; acc.w += v6 * m6.w;
        acc.x += v7 * m7.x; acc.y += v7 * m7.y; acc.z += v7 * m7.z; acc.w += v7 * m7.w;
    }

    out4[(long)node * 16 + t] = acc;
}

extern "C" void kernel_launch(void* const* d_in, const int* in_sizes, int n_in,
                              void* d_out, int out_size, void* d_ws, size_t ws_size,
                              hipStream_t stream) {
    const int*    rows    = (const int*)d_in[0];
    const int*    cols    = (const int*)d_in[1];
    const float*  vals    = (const float*)d_in[2];
    const float4* embeds4 = (const float4*)d_in[3];
    float4*       out4    = (float4*)d_out;

    const int n_edges = in_sizes[0];
    const int n_nodes = out_size / D;     // 100000

    int* row_ptr = (int*)d_ws;            // (n_nodes+1) ints, ~400 KB

    // 1) build CSR row pointers from sorted rows
    int rb = (n_edges + 255) / 256;
    rowptr_kernel<<<rb, 256, 0, stream>>>(rows, row_ptr, n_edges, n_nodes);

    // 2) node-centric SpMM: one 16-lane subgroup per node
    int waves  = (n_nodes + 3) / 4;       // 4 nodes per wave
    int blocks = (waves + 3) / 4;         // 4 waves per 256-thread block
    spmm_node_kernel<<<blocks, 256, 0, stream>>>(row_ptr, cols, vals, embeds4, out4, n_nodes);
}

// Round 5
// 141.669 us; speedup vs baseline: 1.4385x; 1.0029x over previous
//
#include <hip/hip_runtime.h>
#include <hip/hip_bf16.h>

// GCN SpMM: out[i,d] = sum_{e: rows[e]==i} vals[e] * embeds[cols[e], d]
// rows sorted ascending. E=1.6M, N=100k, D=64.
//
// Node-centric CSR, unroll-8 (round 4) + L1-BYPASS GATHERS:
// the embed gathers are random over 25.6 MB (L1 hit ~0%) and round 3/4 showed
// throughput pinned at ~11.5 B/cyc/CU regardless of per-wave MLP -> per-CU
// L1 outstanding-miss cap. Gathers now use raw buffer loads with sc0 (agent
// scope) which are served by L2 directly, skipping the non-coherent L1.
// Metadata loads keep the normal (L1-cached) path.

constexpr int D = 64;

typedef float  vfloat4 __attribute__((ext_vector_type(4)));
typedef int    vint4   __attribute__((ext_vector_type(4)));

// CK-style raw buffer load intrinsic: compiler tracks vmcnt automatically.
extern "C" __device__ vfloat4
llvm_amdgcn_raw_buffer_load_v4f32(vint4 rsrc, int voffset, int soffset, int aux)
    __asm("llvm.amdgcn.raw.buffer.load.v4f32");

__global__ __launch_bounds__(256) void rowptr_kernel(
    const int* __restrict__ rows, int* __restrict__ row_ptr,
    int n_edges, int n_nodes)
{
    int e = blockIdx.x * blockDim.x + threadIdx.x;
    if (e >= n_edges) return;
    int r_cur  = rows[e];
    int r_prev = (e == 0) ? -1 : rows[e - 1];
    for (int r = r_prev + 1; r <= r_cur; ++r) row_ptr[r] = e;
    if (e == n_edges - 1)
        for (int r = r_cur + 1; r <= n_nodes; ++r) row_ptr[r] = n_edges;
}

__global__ __launch_bounds__(256) void spmm_node_kernel(
    const int* __restrict__ row_ptr,
    const int* __restrict__ cols,
    const float* __restrict__ vals,
    const float* __restrict__ embeds,     // [N,64] f32
    float4* __restrict__ out4,            // [N,16] float4 view
    int n_nodes)
{
    const int lane = threadIdx.x & 63;
    const int t    = lane & 15;           // feature quad
    const int s    = lane >> 4;           // subgroup within wave
    const int wave = blockIdx.x * (blockDim.x >> 6) + (threadIdx.x >> 6);
    const int node = wave * 4 + s;
    if (node >= n_nodes) return;

    // SRD for embeds: base, stride=0, num_records = N*64*4 bytes, dword-raw
    union { const float* p; unsigned long long u; int2 i; } eb;
    eb.p = embeds;
    vint4 rsrc;
    rsrc.x = eb.i.x;
    rsrc.y = eb.i.y;                       // high bits; stride=0
    rsrc.z = n_nodes * (D * 4);            // 25,600,000 bytes
    rsrc.w = 0x00020000;                   // raw dword access

    const int lo = row_ptr[node];
    const int hi = row_ptr[node + 1];

    vfloat4 acc = {0.f, 0.f, 0.f, 0.f};
    const int tb = t << 4;                 // byte offset of this lane's quad

    for (int e = lo; e < hi; e += 8) {
        const int last = hi - 1;
        int i0 = e;
        int i1 = (e + 1 <= last) ? e + 1 : last;
        int i2 = (e + 2 <= last) ? e + 2 : last;
        int i3 = (e + 3 <= last) ? e + 3 : last;
        int i4 = (e + 4 <= last) ? e + 4 : last;
        int i5 = (e + 5 <= last) ? e + 5 : last;
        int i6 = (e + 6 <= last) ? e + 6 : last;
        int i7 = (e + 7 <= last) ? e + 7 : last;

        int c0 = cols[i0], c1 = cols[i1], c2 = cols[i2], c3 = cols[i3];
        int c4 = cols[i4], c5 = cols[i5], c6 = cols[i6], c7 = cols[i7];

        float v0 = vals[i0];
        float v1 = (e + 1 < hi) ? vals[i1] : 0.f;
        float v2 = (e + 2 < hi) ? vals[i2] : 0.f;
        float v3 = (e + 3 < hi) ? vals[i3] : 0.f;
        float v4 = (e + 4 < hi) ? vals[i4] : 0.f;
        float v5 = (e + 5 < hi) ? vals[i5] : 0.f;
        float v6 = (e + 6 < hi) ? vals[i6] : 0.f;
        float v7 = (e + 7 < hi) ? vals[i7] : 0.f;

        // 8 independent L1-bypassing gathers (aux=1 -> sc0/agent scope)
        vfloat4 m0 = llvm_amdgcn_raw_buffer_load_v4f32(rsrc, c0 * 256 + tb, 0, 1);
        vfloat4 m1 = llvm_amdgcn_raw_buffer_load_v4f32(rsrc, c1 * 256 + tb, 0, 1);
        vfloat4 m2 = llvm_amdgcn_raw_buffer_load_v4f32(rsrc, c2 * 256 + tb, 0, 1);
        vfloat4 m3 = llvm_amdgcn_raw_buffer_load_v4f32(rsrc, c3 * 256 + tb, 0, 1);
        vfloat4 m4 = llvm_amdgcn_raw_buffer_load_v4f32(rsrc, c4 * 256 + tb, 0, 1);
        vfloat4 m5 = llvm_amdgcn_raw_buffer_load_v4f32(rsrc, c5 * 256 + tb, 0, 1);
        vfloat4 m6 = llvm_amdgcn_raw_buffer_load_v4f32(rsrc, c6 * 256 + tb, 0, 1);
        vfloat4 m7 = llvm_amdgcn_raw_buffer_load_v4f32(rsrc, c7 * 256 + tb, 0, 1);

        acc += v0 * m0;
        acc += v1 * m1;
        acc += v2 * m2;
        acc += v3 * m3;
        acc += v4 * m4;
        acc += v5 * m5;
        acc += v6 * m6;
        acc += v7 * m7;
    }

    float4 res;
    res.x = acc.x; res.y = acc.y; res.z = acc.z; res.w = acc.w;
    out4[(long)node * 16 + t] = res;
}

extern "C" void kernel_launch(void* const* d_in, const int* in_sizes, int n_in,
                              void* d_out, int out_size, void* d_ws, size_t ws_size,
                              hipStream_t stream) {
    const int*   rows   = (const int*)d_in[0];
    const int*   cols   = (const int*)d_in[1];
    const float* vals   = (const float*)d_in[2];
    const float* embeds = (const float*)d_in[3];
    float4*      out4   = (float4*)d_out;

    const int n_edges = in_sizes[0];
    const int n_nodes = out_size / D;     // 100000

    int* row_ptr = (int*)d_ws;            // (n_nodes+1) ints, ~400 KB

    // 1) build CSR row pointers from sorted rows
    int rb = (n_edges + 255) / 256;
    rowptr_kernel<<<rb, 256, 0, stream>>>(rows, row_ptr, n_edges, n_nodes);

    // 2) node-centric SpMM: one 16-lane subgroup per node
    int waves  = (n_nodes + 3) / 4;       // 4 nodes per wave
    int blocks = (waves + 3) / 4;         // 4 waves per 256-thread block
    spmm_node_kernel<<<blocks, 256, 0, stream>>>(row_ptr, cols, vals, embeds, out4, n_nodes);
}

// Round 6
// 127.575 us; speedup vs baseline: 1.5974x; 1.1105x over previous
//
#include <hip/hip_runtime.h>
#include <hip/hip_bf16.h>

// GCN SpMM: out[i,d] = sum_{e: rows[e]==i} vals[e] * embeds[cols[e], d]
// rows sorted ascending. E=1.6M, N=100k, D=64.
//
// Round 6: bf16-compressed gather table.
//  1) cvt_kernel: embeds f32 [N,64] -> bf16 [N,64] in d_ws (RNE). 25.6->12.8MB.
//  2) rowptr_kernel: CSR row_ptr[N+1] from sorted rows (in d_ws after table).
//  3) spmm_node_kernel: one 16-lane subgroup per node; lane t owns features
//     [4t,4t+4). Gather is now 8 B/lane (dwordx2) = 128 B/row: HALF the
//     64B-sector traffic of the f32 version (the measured wall scaled with
//     sector count across rounds 3-5), and the 12.8 MB table doubles the
//     per-XCD L2 hit rate. 8-deep unrolled gather, predicated tail, one
//     coalesced float4 store per node. No atomics, no zero pass.

constexpr int D = 64;

__device__ __forceinline__ unsigned bf16rnd(unsigned u) {
    // round-to-nearest-even f32 -> bf16 (returns low 16 bits)
    return (u + 0x7FFFu + ((u >> 16) & 1u)) >> 16;
}

__global__ __launch_bounds__(256) void cvt_kernel(
    const uint4* __restrict__ src,   // f32 embeds as uint4, 2 per group of 8
    uint4* __restrict__ dst,         // bf16 embeds as uint4 (8 bf16)
    int n8)                          // number of 8-float groups
{
    int i = blockIdx.x * blockDim.x + threadIdx.x;
    if (i >= n8) return;
    uint4 a = src[2 * i];
    uint4 b = src[2 * i + 1];
    uint4 o;
    o.x = bf16rnd(a.x) | (bf16rnd(a.y) << 16);
    o.y = bf16rnd(a.z) | (bf16rnd(a.w) << 16);
    o.z = bf16rnd(b.x) | (bf16rnd(b.y) << 16);
    o.w = bf16rnd(b.z) | (bf16rnd(b.w) << 16);
    dst[i] = o;
}

__global__ __launch_bounds__(256) void rowptr_kernel(
    const int* __restrict__ rows, int* __restrict__ row_ptr,
    int n_edges, int n_nodes)
{
    int e = blockIdx.x * blockDim.x + threadIdx.x;
    if (e >= n_edges) return;
    int r_cur  = rows[e];
    int r_prev = (e == 0) ? -1 : rows[e - 1];
    for (int r = r_prev + 1; r <= r_cur; ++r) row_ptr[r] = e;
    if (e == n_edges - 1)
        for (int r = r_cur + 1; r <= n_nodes; ++r) row_ptr[r] = n_edges;
}

__device__ __forceinline__ float bflo(unsigned w) {
    union { unsigned u; float f; } x; x.u = w << 16; return x.f;
}
__device__ __forceinline__ float bfhi(unsigned w) {
    union { unsigned u; float f; } x; x.u = w & 0xFFFF0000u; return x.f;
}

__global__ __launch_bounds__(256) void spmm_node_kernel(
    const int* __restrict__ row_ptr,
    const int* __restrict__ cols,
    const float* __restrict__ vals,
    const uint2* __restrict__ ebf,        // bf16 [N,64]: row = 16 uint2
    float4* __restrict__ out4,            // [N,16] float4 view
    int n_nodes)
{
    const int lane = threadIdx.x & 63;
    const int t    = lane & 15;           // feature quad
    const int s    = lane >> 4;           // subgroup within wave
    const int wave = blockIdx.x * (blockDim.x >> 6) + (threadIdx.x >> 6);
    const int node = wave * 4 + s;
    if (node >= n_nodes) return;

    const int lo = row_ptr[node];
    const int hi = row_ptr[node + 1];

    float4 acc = make_float4(0.f, 0.f, 0.f, 0.f);

    for (int e = lo; e < hi; e += 8) {
        const int last = hi - 1;
        int i0 = e;
        int i1 = (e + 1 <= last) ? e + 1 : last;
        int i2 = (e + 2 <= last) ? e + 2 : last;
        int i3 = (e + 3 <= last) ? e + 3 : last;
        int i4 = (e + 4 <= last) ? e + 4 : last;
        int i5 = (e + 5 <= last) ? e + 5 : last;
        int i6 = (e + 6 <= last) ? e + 6 : last;
        int i7 = (e + 7 <= last) ? e + 7 : last;

        int c0 = cols[i0], c1 = cols[i1], c2 = cols[i2], c3 = cols[i3];
        int c4 = cols[i4], c5 = cols[i5], c6 = cols[i6], c7 = cols[i7];

        float v0 = vals[i0];
        float v1 = (e + 1 < hi) ? vals[i1] : 0.f;
        float v2 = (e + 2 < hi) ? vals[i2] : 0.f;
        float v3 = (e + 3 < hi) ? vals[i3] : 0.f;
        float v4 = (e + 4 < hi) ? vals[i4] : 0.f;
        float v5 = (e + 5 < hi) ? vals[i5] : 0.f;
        float v6 = (e + 6 < hi) ? vals[i6] : 0.f;
        float v7 = (e + 7 < hi) ? vals[i7] : 0.f;

        // 8 independent 8-byte gathers (dwordx2), all live -> 8-deep MLP
        uint2 m0 = ebf[c0 * 16 + t];
        uint2 m1 = ebf[c1 * 16 + t];
        uint2 m2 = ebf[c2 * 16 + t];
        uint2 m3 = ebf[c3 * 16 + t];
        uint2 m4 = ebf[c4 * 16 + t];
        uint2 m5 = ebf[c5 * 16 + t];
        uint2 m6 = ebf[c6 * 16 + t];
        uint2 m7 = ebf[c7 * 16 + t];

        acc.x += v0 * bflo(m0.x); acc.y += v0 * bfhi(m0.x);
        acc.z += v0 * bflo(m0.y); acc.w += v0 * bfhi(m0.y);
        acc.x += v1 * bflo(m1.x); acc.y += v1 * bfhi(m1.x);
        acc.z += v1 * bflo(m1.y); acc.w += v1 * bfhi(m1.y);
        acc.x += v2 * bflo(m2.x); acc.y += v2 * bfhi(m2.x);
        acc.z += v2 * bflo(m2.y); acc.w += v2 * bfhi(m2.y);
        acc.x += v3 * bflo(m3.x); acc.y += v3 * bfhi(m3.x);
        acc.z += v3 * bflo(m3.y); acc.w += v3 * bfhi(m3.y);
        acc.x += v4 * bflo(m4.x); acc.y += v4 * bfhi(m4.x);
        acc.z += v4 * bflo(m4.y); acc.w += v4 * bfhi(m4.y);
        acc.x += v5 * bflo(m5.x); acc.y += v5 * bfhi(m5.x);
        acc.z += v5 * bflo(m5.y); acc.w += v5 * bfhi(m5.y);
        acc.x += v6 * bflo(m6.x); acc.y += v6 * bfhi(m6.x);
        acc.z += v6 * bflo(m6.y); acc.w += v6 * bfhi(m6.y);
        acc.x += v7 * bflo(m7.x); acc.y += v7 * bfhi(m7.x);
        acc.z += v7 * bflo(m7.y); acc.w += v7 * bfhi(m7.y);
    }

    out4[(long)node * 16 + t] = acc;
}

extern "C" void kernel_launch(void* const* d_in, const int* in_sizes, int n_in,
                              void* d_out, int out_size, void* d_ws, size_t ws_size,
                              hipStream_t stream) {
    const int*   rows   = (const int*)d_in[0];
    const int*   cols   = (const int*)d_in[1];
    const float* vals   = (const float*)d_in[2];
    const float* embeds = (const float*)d_in[3];
    float4*      out4   = (float4*)d_out;

    const int n_edges = in_sizes[0];
    const int n_nodes = out_size / D;                 // 100000
    const int n_feat  = in_sizes[3];                  // 6,400,000

    char* ws = (char*)d_ws;
    uint4* ebf_table = (uint4*)ws;                    // 12.8 MB bf16 table
    int*   row_ptr   = (int*)(ws + (size_t)n_feat * 2); // +12,800,000 B

    // 1) f32 -> bf16 embedding table
    int n8 = n_feat / 8;                              // 800,000 groups
    cvt_kernel<<<(n8 + 255) / 256, 256, 0, stream>>>(
        (const uint4*)embeds, ebf_table, n8);

    // 2) CSR row pointers from sorted rows
    rowptr_kernel<<<(n_edges + 255) / 256, 256, 0, stream>>>(
        rows, row_ptr, n_edges, n_nodes);

    // 3) node-centric SpMM: one 16-lane subgroup per node
    int waves  = (n_nodes + 3) / 4;                   // 4 nodes per wave
    int blocks = (waves + 3) / 4;                     // 4 waves per block
    spmm_node_kernel<<<blocks, 256, 0, stream>>>(
        row_ptr, cols, vals, (const uint2*)ebf_table, out4, n_nodes);
}

// Round 7
// 122.226 us; speedup vs baseline: 1.6674x; 1.0438x over previous
//
#include <hip/hip_runtime.h>
#include <hip/hip_bf16.h>

// GCN SpMM: out[i,d] = sum_{e: rows[e]==i} vals[e] * embeds[cols[e], d]
// rows sorted ascending. E=1.6M, N=100k, D=64.
//
// Round 7:
//  1) prep_kernel (merged): blocks [0,cvt_blocks) convert embeds f32->bf16
//     (12.8 MB table in d_ws); remaining blocks build CSR row_ptr[N+1].
//  2) spmm_node_kernel: 8-lane subgroups (8 nodes/wave). Lane t owns features
//     [8t,8t+8) as one dwordx4 (16 B) of bf16 -> each gather instruction
//     covers 8 rows (vs 4 before), amortizing the measured ~18 cyc
//     per-instruction TA overhead over 2x the rows. Sector traffic unchanged
//     (2 x 64B sectors per 128 B row). Unroll-4, predicated clamp tail,
//     2 coalesced float4 stores per node-lane. No atomics, no zero pass.

constexpr int D = 64;

__device__ __forceinline__ unsigned bf16rnd(unsigned u) {
    // round-to-nearest-even f32 -> bf16 (low 16 bits)
    return (u + 0x7FFFu + ((u >> 16) & 1u)) >> 16;
}

__global__ __launch_bounds__(256) void prep_kernel(
    const uint4* __restrict__ src,   // f32 embeds as uint4 (2 per 8-float group)
    uint4* __restrict__ dst,         // bf16 table as uint4 (8 bf16)
    int n8,
    const int* __restrict__ rows, int* __restrict__ row_ptr,
    int n_edges, int n_nodes, int cvt_blocks)
{
    if ((int)blockIdx.x < cvt_blocks) {
        int i = blockIdx.x * 256 + threadIdx.x;
        if (i >= n8) return;
        uint4 a = src[2 * i];
        uint4 b = src[2 * i + 1];
        uint4 o;
        o.x = bf16rnd(a.x) | (bf16rnd(a.y) << 16);
        o.y = bf16rnd(a.z) | (bf16rnd(a.w) << 16);
        o.z = bf16rnd(b.x) | (bf16rnd(b.y) << 16);
        o.w = bf16rnd(b.z) | (bf16rnd(b.w) << 16);
        dst[i] = o;
    } else {
        int e = (blockIdx.x - cvt_blocks) * 256 + threadIdx.x;
        if (e >= n_edges) return;
        int r_cur  = rows[e];
        int r_prev = (e == 0) ? -1 : rows[e - 1];
        for (int r = r_prev + 1; r <= r_cur; ++r) row_ptr[r] = e;
        if (e == n_edges - 1)
            for (int r = r_cur + 1; r <= n_nodes; ++r) row_ptr[r] = n_edges;
    }
}

__device__ __forceinline__ float bflo(unsigned w) {
    union { unsigned u; float f; } x; x.u = w << 16; return x.f;
}
__device__ __forceinline__ float bfhi(unsigned w) {
    union { unsigned u; float f; } x; x.u = w & 0xFFFF0000u; return x.f;
}

__global__ __launch_bounds__(256) void spmm_node_kernel(
    const int* __restrict__ row_ptr,
    const int* __restrict__ cols,
    const float* __restrict__ vals,
    const uint4* __restrict__ ebf4,       // bf16 [N,64]: row = 8 uint4
    float4* __restrict__ out4,            // [N,16] float4 view
    int n_nodes)
{
    const int lane = threadIdx.x & 63;
    const int t    = lane & 7;            // 16B chunk within row
    const int s    = lane >> 3;           // subgroup (node) within wave
    const int wave = blockIdx.x * (blockDim.x >> 6) + (threadIdx.x >> 6);
    const int node = wave * 8 + s;
    if (node >= n_nodes) return;

    const int lo = row_ptr[node];
    const int hi = row_ptr[node + 1];

    float4 acc0 = make_float4(0.f, 0.f, 0.f, 0.f);
    float4 acc1 = make_float4(0.f, 0.f, 0.f, 0.f);

    for (int e = lo; e < hi; e += 4) {
        const int last = hi - 1;
        int i0 = e;
        int i1 = (e + 1 <= last) ? e + 1 : last;
        int i2 = (e + 2 <= last) ? e + 2 : last;
        int i3 = (e + 3 <= last) ? e + 3 : last;

        int c0 = cols[i0], c1 = cols[i1], c2 = cols[i2], c3 = cols[i3];

        float v0 = vals[i0];
        float v1 = (e + 1 < hi) ? vals[i1] : 0.f;
        float v2 = (e + 2 < hi) ? vals[i2] : 0.f;
        float v3 = (e + 3 < hi) ? vals[i3] : 0.f;

        // 4 independent dwordx4 gathers; each instruction covers 8 rows
        uint4 m0 = ebf4[c0 * 8 + t];
        uint4 m1 = ebf4[c1 * 8 + t];
        uint4 m2 = ebf4[c2 * 8 + t];
        uint4 m3 = ebf4[c3 * 8 + t];

        acc0.x += v0 * bflo(m0.x); acc0.y += v0 * bfhi(m0.x);
        acc0.z += v0 * bflo(m0.y); acc0.w += v0 * bfhi(m0.y);
        acc1.x += v0 * bflo(m0.z); acc1.y += v0 * bfhi(m0.z);
        acc1.z += v0 * bflo(m0.w); acc1.w += v0 * bfhi(m0.w);

        acc0.x += v1 * bflo(m1.x); acc0.y += v1 * bfhi(m1.x);
        acc0.z += v1 * bflo(m1.y); acc0.w += v1 * bfhi(m1.y);
        acc1.x += v1 * bflo(m1.z); acc1.y += v1 * bfhi(m1.z);
        acc1.z += v1 * bflo(m1.w); acc1.w += v1 * bfhi(m1.w);

        acc0.x += v2 * bflo(m2.x); acc0.y += v2 * bfhi(m2.x);
        acc0.z += v2 * bflo(m2.y); acc0.w += v2 * bfhi(m2.y);
        acc1.x += v2 * bflo(m2.z); acc1.y += v2 * bfhi(m2.z);
        acc1.z += v2 * bflo(m2.w); acc1.w += v2 * bfhi(m2.w);

        acc0.x += v3 * bflo(m3.x); acc0.y += v3 * bfhi(m3.x);
        acc0.z += v3 * bflo(m3.y); acc0.w += v3 * bfhi(m3.y);
        acc1.x += v3 * bflo(m3.z); acc1.y += v3 * bfhi(m3.z);
        acc1.z += v3 * bflo(m3.w); acc1.w += v3 * bfhi(m3.w);
    }

    long ob = (long)node * 16 + 2 * t;    // lane writes features [8t, 8t+8)
    out4[ob]     = acc0;
    out4[ob + 1] = acc1;
}

extern "C" void kernel_launch(void* const* d_in, const int* in_sizes, int n_in,
                              void* d_out, int out_size, void* d_ws, size_t ws_size,
                              hipStream_t stream) {
    const int*   rows   = (const int*)d_in[0];
    const int*   cols   = (const int*)d_in[1];
    const float* vals   = (const float*)d_in[2];
    const float* embeds = (const float*)d_in[3];
    float4*      out4   = (float4*)d_out;

    const int n_edges = in_sizes[0];
    const int n_nodes = out_size / D;                 // 100000
    const int n_feat  = in_sizes[3];                  // 6,400,000

    char*  ws        = (char*)d_ws;
    uint4* ebf_table = (uint4*)ws;                    // 12.8 MB bf16 table
    int*   row_ptr   = (int*)(ws + (size_t)n_feat * 2);

    // 1) merged prep: f32->bf16 table + CSR row pointers
    int n8         = n_feat / 8;                      // 800,000 groups
    int cvt_blocks = (n8 + 255) / 256;                // 3125
    int row_blocks = (n_edges + 255) / 256;           // 6250
    prep_kernel<<<cvt_blocks + row_blocks, 256, 0, stream>>>(
        (const uint4*)embeds, ebf_table, n8,
        rows, row_ptr, n_edges, n_nodes, cvt_blocks);

    // 2) node-centric SpMM: one 8-lane subgroup per node
    int waves  = (n_nodes + 7) / 8;                   // 8 nodes per wave
    int blocks = (waves + 3) / 4;                     // 4 waves per block
    spmm_node_kernel<<<blocks, 256, 0, stream>>>(
        row_ptr, cols, vals, ebf_table, out4, n_nodes);
}